// Round 8
// baseline (1122.539 us; speedup 1.0000x reference)
//
#include <hip/hip_runtime.h>

typedef float v2f __attribute__((ext_vector_type(2)));

#define SUB   8
#define INCH  64
#define IMH   128
#define IMW   128
#define OUTCH 128
#define OH    126
#define OW    126
#define OPLANE (OH * OW)     // 15876

#define NCH   15             // 8 owned och-pairs + 7 halo channels
#define ROWW  128            // words per channel row (full width, no pad: gload_lds linear)
#define BUFW  (NCH * ROWW)   // 1920 words = 7680 B per row-buffer

// ---- weight prep: chunk c = s*64 + p (p in [0,64)): 20 floats, 16B aligned
//      t0..8 = W[p][s][.][.],  t9..17 = W[p+64][s][.][.]
__global__ __launch_bounds__(256)
void prep_weights_kernel(const float* __restrict__ Wg, float* __restrict__ Wp) {
    int idx = blockIdx.x * 256 + threadIdx.x;
    if (idx < 512 * 18) {
        int chunk = idx / 18;
        int t     = idx - chunk * 18;
        int s = chunk >> 6;
        int p = chunk & 63;
        int o  = (t < 9) ? p : p + 64;
        int tt = (t < 9) ? t : t - 9;
        Wp[chunk * 20 + t] = Wg[(o * SUB + s) * 9 + tt];
    }
}

// y-walking column kernel. Block = 8 och-pairs x 128 cols x 32-row strip.
// Thread (pl, xg) = 2 och x 4 cols, walks 34 input rows; 3-slot output ring.
// Weights resident in VGPRs (144); launch_bounds(256,2) -> 256 VGPR cap, 2 blocks/CU.
__global__ __launch_bounds__(256, 2)
void Group_Conv_84731114815961_kernel(const float* __restrict__ X,
                                      const float* __restrict__ Wg,
                                      const float* __restrict__ Bias,
                                      const float* __restrict__ Wp,
                                      float* __restrict__ Out) {
    __shared__ float xin[2 * BUFW];   // 15360 B double-buffered row set

    const int g   = blockIdx.x;   // 0..7  och-pair group (p = 8g..8g+7)
    const int ty  = blockIdx.y;   // 0..3  32-row strip
    const int b   = blockIdx.z;   // 0..15
    const int y0  = ty * 32;
    const int tid = threadIdx.x;
    const int pl  = tid >> 5;     // 0..7  local och-pair
    const int xg  = tid & 31;     // 4-col group (x = 4xg..4xg+3)
    const int o0  = g * 8 + pl;   // och pair {o0, o0+64}

    const float* Xb = X + (size_t)b * INCH * IMH * IMW;

    // staging: 480 float4 per row-set; thread covers k=tid and k=256+tid (tid<224)
    const int    c0   = (g * 8 + pl) & 63;
    const int    c1   = (g * 8 + 8 + pl) & 63;          // wraps for g=7
    const size_t so0  = (size_t)c0 * (IMH * IMW) + (size_t)xg * 4;
    const size_t so1  = (size_t)c1 * (IMH * IMW) + (size_t)xg * 4;
    const bool   act1 = (tid < 224);

#define STAGE(nb_, row_) do {                                                          \
    int r_ = (row_); if (r_ > IMH - 1) r_ = IMH - 1;                                   \
    __builtin_amdgcn_global_load_lds(                                                  \
        (const __attribute__((address_space(1))) void*)(Xb + so0 + (size_t)r_ * IMW),  \
        (__attribute__((address_space(3))) void*)(&xin[(nb_) * BUFW + tid * 4]),       \
        16, 0, 0);                                                                     \
    if (act1) __builtin_amdgcn_global_load_lds(                                        \
        (const __attribute__((address_space(1))) void*)(Xb + so1 + (size_t)r_ * IMW),  \
        (__attribute__((address_space(3))) void*)(&xin[(nb_) * BUFW + (256 + tid) * 4]),\
        16, 0, 0);                                                                     \
} while (0)

    // ---- resident weights: w[och-half][s][tap] ----
    float w[2][8][9];
    if (Wp) {
        #pragma unroll
        for (int s = 0; s < 8; ++s) {
            const float4* wc = reinterpret_cast<const float4*>(Wp + ((s << 6) + o0) * 20);
            const float4 f0 = wc[0], f1 = wc[1], f2 = wc[2], f3 = wc[3], f4 = wc[4];
            w[0][s][0]=f0.x; w[0][s][1]=f0.y; w[0][s][2]=f0.z; w[0][s][3]=f0.w;
            w[0][s][4]=f1.x; w[0][s][5]=f1.y; w[0][s][6]=f1.z; w[0][s][7]=f1.w;
            w[0][s][8]=f2.x;
            w[1][s][0]=f2.y; w[1][s][1]=f2.z; w[1][s][2]=f2.w;
            w[1][s][3]=f3.x; w[1][s][4]=f3.y; w[1][s][5]=f3.z; w[1][s][6]=f3.w;
            w[1][s][7]=f4.x; w[1][s][8]=f4.y;
        }
    } else {
        #pragma unroll
        for (int s = 0; s < 8; ++s)
            #pragma unroll
            for (int t = 0; t < 9; ++t) {
                w[0][s][t] = Wg[(o0 * SUB + s) * 9 + t];
                w[1][s][t] = Wg[((o0 + 64) * SUB + s) * 9 + t];
            }
    }

    const float bz0 = Bias[o0];
    const float bz1 = Bias[o0 + 64];

    // acc[ring slot][och half][col pair]; init = bias (folds epilogue add)
    v2f acc[3][2][2];
    #pragma unroll
    for (int sl = 0; sl < 3; ++sl) {
        acc[sl][0][0] = v2f{bz0, bz0}; acc[sl][0][1] = v2f{bz0, bz0};
        acc[sl][1][0] = v2f{bz1, bz1}; acc[sl][1][1] = v2f{bz1, bz1};
    }

    float* ob0 = Out + ((size_t)(b * OUTCH + o0)) * OPLANE + (size_t)xg * 4;
    float* ob1 = ob0 + (size_t)64 * OPLANE;

    STAGE(0, y0);
    __syncthreads();

    int rr = 0;   // step index: input row y0+rr

// One y-step: stage row rr+1 -> buf[(rr+1)&1]; compute row rr from buf[rr&1];
// input row rr contributes rowsum_i to out[rr-i], slot (rr-i)%3; store slot
// (PHI+1)%3 (= out rr-2) when DOSTORE; one barrier per step.
#define STEP(PHI_, IMIN_, IMAX_, DOSTORE_, DOSTAGE_) do {                              \
    const float* bufc_ = &xin[(rr & 1) * BUFW];                                        \
    if (DOSTAGE_) STAGE((rr + 1) & 1, y0 + rr + 1);                                    \
    _Pragma("unroll")                                                                  \
    for (int s_ = 0; s_ < 8; ++s_) {                                                   \
        const float* ba_ = bufc_ + (pl + s_) * ROWW + xg * 4;                          \
        const float4 a_ = *reinterpret_cast<const float4*>(ba_);                       \
        const float2 e_ = *reinterpret_cast<const float2*>(ba_ + 4);                   \
        v2f vp_[5];                                                                    \
        vp_[0] = v2f{a_.x, a_.y}; vp_[1] = v2f{a_.y, a_.z}; vp_[2] = v2f{a_.z, a_.w};  \
        vp_[3] = v2f{a_.w, e_.x}; vp_[4] = v2f{e_.x, e_.y};                            \
        _Pragma("unroll")                                                              \
        for (int i_ = (IMIN_); i_ <= (IMAX_); ++i_) {                                  \
            const int sl_ = ((PHI_) - i_ + 3) % 3;                                     \
            _Pragma("unroll")                                                          \
            for (int j_ = 0; j_ < 3; ++j_) {                                           \
                const float ws0_ = w[0][s_][3 * i_ + j_];                              \
                const float ws1_ = w[1][s_][3 * i_ + j_];                              \
                const v2f w0_ = v2f{ws0_, ws0_};                                       \
                const v2f w1_ = v2f{ws1_, ws1_};                                       \
                acc[sl_][0][0] = __builtin_elementwise_fma(vp_[j_],     w0_, acc[sl_][0][0]); \
                acc[sl_][0][1] = __builtin_elementwise_fma(vp_[j_ + 2], w0_, acc[sl_][0][1]); \
                acc[sl_][1][0] = __builtin_elementwise_fma(vp_[j_],     w1_, acc[sl_][1][0]); \
                acc[sl_][1][1] = __builtin_elementwise_fma(vp_[j_ + 2], w1_, acc[sl_][1][1]); \
            }                                                                          \
        }                                                                              \
    }                                                                                  \
    if (DOSTORE_) {                                                                    \
        const int st_ = ((PHI_) + 1) % 3;                                              \
        const int oy_ = y0 + rr - 2;                                                   \
        float* p0_ = ob0 + (size_t)oy_ * OW;                                           \
        float* p1_ = ob1 + (size_t)oy_ * OW;                                           \
        if (xg < 31) {                                                                 \
            *reinterpret_cast<float4*>(p0_) = make_float4(                             \
                acc[st_][0][0].x, acc[st_][0][0].y, acc[st_][0][1].x, acc[st_][0][1].y); \
            *reinterpret_cast<float4*>(p1_) = make_float4(                             \
                acc[st_][1][0].x, acc[st_][1][0].y, acc[st_][1][1].x, acc[st_][1][1].y); \
        } else {  /* x=124,125 only */                                                 \
            *reinterpret_cast<float2*>(p0_) = make_float2(acc[st_][0][0].x, acc[st_][0][0].y); \
            *reinterpret_cast<float2*>(p1_) = make_float2(acc[st_][1][0].x, acc[st_][1][0].y); \
        }                                                                              \
        acc[st_][0][0] = v2f{bz0, bz0}; acc[st_][0][1] = v2f{bz0, bz0};                \
        acc[st_][1][0] = v2f{bz1, bz1}; acc[st_][1][1] = v2f{bz1, bz1};                \
    }                                                                                  \
    __syncthreads();                                                                   \
    ++rr;                                                                              \
} while (0)

    // prologue: rr=0 (i=0 only), rr=1 (i=0,1) — earlier-i terms belong to prev strip
    STEP(0, 0, 0, false, true);
    STEP(1, 0, 1, false, true);

    // main: rr=2..31, phases [2,0,1] x 10, store out rows y0..y0+29
    #pragma unroll 1
    for (int t = 0; t < 10; ++t) {
        STEP(2, 0, 2, true, true);
        STEP(0, 0, 2, true, true);
        STEP(1, 0, 2, true, true);
    }

    // tail: out rows y0+30, y0+31 (strips 0..2 only; ty=3 ends at out row 125)
    if (ty < 3) {
        STEP(2, 1, 2, true, true);    // rr=32
        STEP(0, 2, 2, true, false);   // rr=33
    }

#undef STEP
#undef STAGE
}

extern "C" void kernel_launch(void* const* d_in, const int* in_sizes, int n_in,
                              void* d_out, int out_size, void* d_ws, size_t ws_size,
                              hipStream_t stream) {
    const float* X    = (const float*)d_in[0];
    const float* Wg   = (const float*)d_in[1];
    const float* Bias = (const float*)d_in[2];
    float*       Out  = (float*)d_out;

    float* Wp = nullptr;
    if (d_ws && ws_size >= 512 * 20 * sizeof(float)) {
        Wp = (float*)d_ws;
        prep_weights_kernel<<<36, 256, 0, stream>>>(Wg, Wp);
    }

    // 8 och-groups x 4 y-strips x 16 batches = 512 blocks = 2/CU, fully resident
    dim3 grid(8, 4, 16);
    Group_Conv_84731114815961_kernel<<<grid, 256, 0, stream>>>(X, Wg, Bias, Wp, Out);
}